// Round 2
// baseline (814.866 us; speedup 1.0000x reference)
//
#include <hip/hip_runtime.h>
#include <hip/hip_bf16.h>

typedef unsigned short u16;
typedef unsigned int u32;
typedef __bf16 bf16x8_t __attribute__((ext_vector_type(8)));
typedef float f32x4_t __attribute__((ext_vector_type(4)));

#define TILE 128
#define BK 32

__device__ __forceinline__ float b2f(u16 v) {
  return __uint_as_float(((u32)v) << 16);
}
__device__ __forceinline__ u16 f2b(float f) {
  __hip_bfloat16 h = __float2bfloat16(f);
  return *reinterpret_cast<u16*>(&h);
}

__device__ __forceinline__ void async_lds16(const u16* g, u16* l) {
  __builtin_amdgcn_global_load_lds(
      (__attribute__((address_space(1))) void*)g,
      (__attribute__((address_space(3))) void*)l, 16, 0, 0);
}

// fp32 -> bf16, 8 elements per thread; n8 = total/8 threads launched exactly.
__global__ __launch_bounds__(256) void cvt_kernel(const float* __restrict__ src,
                                                  u16* __restrict__ dst) {
  const size_t i = ((size_t)blockIdx.x * 256 + threadIdx.x) * 8;
  float4 a = *(const float4*)(src + i);
  float4 b = *(const float4*)(src + i + 4);
  u16 t[8] = {f2b(a.x), f2b(a.y), f2b(a.z), f2b(a.w),
              f2b(b.x), f2b(b.y), f2b(b.z), f2b(b.w)};
  *(uint4*)(dst + i) = *(const uint4*)t;
}

// dst[n*K + k] = bf16(w[((n>>3)*I + (k>>3))*8 + ((n-k)&7)]),  K = gridDim.x*256
__global__ __launch_bounds__(256) void expand_kernel(const float* __restrict__ w,
                                                     u16* __restrict__ dst, int I) {
  const int K = gridDim.x * 256;
  const int k = blockIdx.x * 256 + threadIdx.x;
  const int n = blockIdx.y;
  dst[(size_t)n * K + k] = f2b(w[(size_t)((n >> 3) * I + (k >> 3)) * 8 + ((n - k) & 7)]);
}

// Y[m,n] = sum_k X[m,k]*W[n,k] + bias[n>>3] (+ res[m,n]); X,W bf16, accum fp32.
// Output bf16 (OUT_F32=false) or fp32 (OUT_F32=true). M,N mult of 128; K mult of 32.
template <bool HAS_RES, bool OUT_F32>
__global__ __launch_bounds__(256) void gemm_bt(
    const u16* __restrict__ X, const u16* __restrict__ W,
    const float* __restrict__ bias, const float* __restrict__ res,
    void* __restrict__ Yv, int M, int N, int K) {
  __shared__ __align__(16) u16 As[TILE * BK];
  __shared__ __align__(16) u16 Bs[TILE * BK];
  const int tid = threadIdx.x;
  const int m0 = blockIdx.y * TILE;
  const int n0 = blockIdx.x * TILE;
  const int lane = tid & 63;
  const int wave = tid >> 6;
  const int wm = (wave >> 1) * 64;
  const int wn = (wave & 1) * 64;
  const int l16 = lane & 15;
  const int quad = lane >> 4;

  f32x4_t acc[4][4] = {};

  const int row0 = tid >> 2;       // 0..63
  const int kg0 = (tid & 3) * 8;   // 0,8,16,24

  for (int k0 = 0; k0 < K; k0 += BK) {
#pragma unroll
    for (int it = 0; it < 2; ++it) {
      const int row = row0 + it * 64;
      const int cc = tid + it * 256;
      async_lds16(X + (size_t)(m0 + row) * K + (k0 + kg0), &As[cc * 8]);
      async_lds16(W + (size_t)(n0 + row) * K + (k0 + kg0), &Bs[cc * 8]);
    }
    __syncthreads();
    bf16x8_t af[4], bfr[4];
#pragma unroll
    for (int i = 0; i < 4; ++i)
      af[i] = *(const bf16x8_t*)&As[(wm + i * 16 + l16) * BK + quad * 8];
#pragma unroll
    for (int j = 0; j < 4; ++j)
      bfr[j] = *(const bf16x8_t*)&Bs[(wn + j * 16 + l16) * BK + quad * 8];
#pragma unroll
    for (int i = 0; i < 4; ++i)
#pragma unroll
      for (int j = 0; j < 4; ++j)
        acc[i][j] = __builtin_amdgcn_mfma_f32_16x16x32_bf16(af[i], bfr[j], acc[i][j], 0, 0, 0);
    __syncthreads();
  }

#pragma unroll
  for (int j = 0; j < 4; ++j) {
    const int col = n0 + wn + j * 16 + l16;
    const float bv = bias[col >> 3];
#pragma unroll
    for (int i = 0; i < 4; ++i) {
#pragma unroll
      for (int r = 0; r < 4; ++r) {
        const int rw = m0 + wm + i * 16 + quad * 4 + r;
        float vv = acc[i][j][r] + bv;
        if (HAS_RES) vv += res[(size_t)rw * N + col];
        if (OUT_F32)
          ((float*)Yv)[(size_t)rw * N + col] = vv;
        else
          ((u16*)Yv)[(size_t)rw * N + col] = f2b(vv);
      }
    }
  }
}

// One wave per (b,h) pair. qp/kp/vp: [chunkB,4096] bf16 with layout g*512+h*64+d.
// probs: fp32 out, 64 contiguous per pair (= [b,h,qg,kg]). o: bf16 at g*512+h*64+d.
__global__ __launch_bounds__(256) void attn_kernel(
    const u16* __restrict__ qp, const u16* __restrict__ kp,
    const u16* __restrict__ vp, float* __restrict__ probs,
    u16* __restrict__ o) {
  __shared__ __align__(16) u16 Qs[4][8 * 72];
  __shared__ __align__(16) u16 Ks[4][8 * 72];
  __shared__ __align__(16) u16 Vs[4][8 * 72];
  __shared__ float Ps[4][64];
  const int tid = threadIdx.x;
  const int wave = tid >> 6;
  const int lane = tid & 63;
  const int pair = blockIdx.x * 4 + wave;
  const int b = pair >> 3;
  const int h = pair & 7;
  {
    const int r = lane >> 3, c = lane & 7;
    const size_t g = (size_t)b * 4096 + (size_t)r * 512 + h * 64 + c * 8;
    const int ls = r * 72 + c * 8;
    *(uint4*)&Qs[wave][ls] = *(const uint4*)(qp + g);
    *(uint4*)&Ks[wave][ls] = *(const uint4*)(kp + g);
    *(uint4*)&Vs[wave][ls] = *(const uint4*)(vp + g);
  }
  __syncthreads();
  const int qg = lane >> 3;
  const int kg = lane & 7;
  float s = 0.f;
#pragma unroll
  for (int d = 0; d < 64; ++d)
    s += b2f(Qs[wave][qg * 72 + d]) * b2f(Ks[wave][kg * 72 + d]);
  s *= 0.125f;  // 1/sqrt(dk)
  float mx = s;
  mx = fmaxf(mx, __shfl_xor(mx, 1));
  mx = fmaxf(mx, __shfl_xor(mx, 2));
  mx = fmaxf(mx, __shfl_xor(mx, 4));
  float e = __expf(s - mx);
  float sum = e;
  sum += __shfl_xor(sum, 1);
  sum += __shfl_xor(sum, 2);
  sum += __shfl_xor(sum, 4);
  const float p = e / sum;
  probs[(size_t)pair * 64 + lane] = p;
  Ps[wave][lane] = p;
  __syncthreads();
  float vc[8];
#pragma unroll
  for (int k2 = 0; k2 < 8; ++k2) vc[k2] = b2f(Vs[wave][k2 * 72 + lane]);
#pragma unroll
  for (int q2 = 0; q2 < 8; ++q2) {
    float acc = 0.f;
#pragma unroll
    for (int k2 = 0; k2 < 8; ++k2) acc += Ps[wave][q2 * 8 + k2] * vc[k2];
    o[(size_t)b * 4096 + q2 * 512 + h * 64 + lane] = f2b(acc);
  }
}

extern "C" void kernel_launch(void* const* d_in, const int* in_sizes, int n_in,
                              void* d_out, int out_size, void* d_ws, size_t ws_size,
                              hipStream_t stream) {
  const float* q = (const float*)d_in[0];
  const float* k = (const float*)d_in[1];
  const float* v = (const float*)d_in[2];
  const float* w_q = (const float*)d_in[3];
  const float* b_q = (const float*)d_in[4];
  const float* w_k = (const float*)d_in[5];
  const float* b_k = (const float*)d_in[6];
  const float* w_v = (const float*)d_in[7];
  const float* b_v = (const float*)d_in[8];
  const float* w_fc = (const float*)d_in[9];
  const float* b_fc = (const float*)d_in[10];

  const int B = in_sizes[0] / 1024;  // 8192
  float* out = (float*)d_out;                   // B*1024 fp32
  float* probs = out + (size_t)B * 1024;        // B*512 fp32 (attn)

  // workspace layout (all bf16 = u16)
  u16* Wq = (u16*)d_ws;
  u16* Wk = Wq + (size_t)4096 * 1024;
  u16* Wv = Wk + (size_t)4096 * 1024;
  u16* Wfc = Wv + (size_t)4096 * 1024;  // 1024x4096
  u16* scratch = Wfc + (size_t)4096 * 1024;
  const size_t wbytes = (size_t)4 * 4096 * 1024 * sizeof(u16);

  // per-row scratch: qb,kb,vb (1024 each) + qp,kp,vp,ao (4096 each), bf16
  const size_t per_row = (size_t)(3 * 1024 + 4 * 4096) * sizeof(u16);
  int chunkB = 128;
  for (int c = B; c >= 128; c >>= 1) {
    if (wbytes + (size_t)c * per_row <= ws_size) { chunkB = c; break; }
  }

  // expand circulant weights (fp32 -> bf16)
  expand_kernel<<<dim3(4, 4096), 256, 0, stream>>>(w_q, Wq, 128);
  expand_kernel<<<dim3(4, 4096), 256, 0, stream>>>(w_k, Wk, 128);
  expand_kernel<<<dim3(4, 4096), 256, 0, stream>>>(w_v, Wv, 128);
  expand_kernel<<<dim3(16, 1024), 256, 0, stream>>>(w_fc, Wfc, 512);

  u16* qb = scratch;
  u16* kb = qb + (size_t)chunkB * 1024;
  u16* vb = kb + (size_t)chunkB * 1024;
  u16* qp = vb + (size_t)chunkB * 1024;
  u16* kp = qp + (size_t)chunkB * 4096;
  u16* vp = kp + (size_t)chunkB * 4096;
  u16* ao = vp + (size_t)chunkB * 4096;

  for (int cs = 0; cs < B; cs += chunkB) {
    const int cvtBlocks = chunkB / 2;  // chunkB*1024 elems / 8 per thread / 256
    cvt_kernel<<<cvtBlocks, 256, 0, stream>>>(q + (size_t)cs * 1024, qb);
    cvt_kernel<<<cvtBlocks, 256, 0, stream>>>(k + (size_t)cs * 1024, kb);
    cvt_kernel<<<cvtBlocks, 256, 0, stream>>>(v + (size_t)cs * 1024, vb);

    dim3 gp(4096 / TILE, chunkB / TILE);
    gemm_bt<false, false><<<gp, 256, 0, stream>>>(qb, Wq, b_q, nullptr, qp,
                                                  chunkB, 4096, 1024);
    gemm_bt<false, false><<<gp, 256, 0, stream>>>(kb, Wk, b_k, nullptr, kp,
                                                  chunkB, 4096, 1024);
    gemm_bt<false, false><<<gp, 256, 0, stream>>>(vb, Wv, b_v, nullptr, vp,
                                                  chunkB, 4096, 1024);
    attn_kernel<<<chunkB * 2, 256, 0, stream>>>(qp, kp, vp,
                                                probs + (size_t)cs * 512, ao);
    gemm_bt<true, true><<<dim3(1024 / TILE, chunkB / TILE), 256, 0, stream>>>(
        ao, Wfc, b_fc, q + (size_t)cs * 1024, out + (size_t)cs * 1024,
        chunkB, 1024, 4096);
  }
}

// Round 3
// 755.855 us; speedup vs baseline: 1.0781x; 1.0781x over previous
//
#include <hip/hip_runtime.h>
#include <hip/hip_bf16.h>

typedef unsigned short u16;
typedef unsigned int u32;
typedef __bf16 bf16x8_t __attribute__((ext_vector_type(8)));
typedef float f32x4_t __attribute__((ext_vector_type(4)));

#define TILE 128
#define BK 32

__device__ __forceinline__ float b2f(u16 v) {
  return __uint_as_float(((u32)v) << 16);
}
__device__ __forceinline__ u16 f2b(float f) {
  __hip_bfloat16 h = __float2bfloat16(f);
  return *reinterpret_cast<u16*>(&h);
}
__device__ __forceinline__ float blo(u32 u) { return __uint_as_float(u << 16); }
__device__ __forceinline__ float bhi(u32 u) { return __uint_as_float(u & 0xffff0000u); }

__device__ __forceinline__ void async_lds16(const u16* g, u16* l) {
  __builtin_amdgcn_global_load_lds(
      (__attribute__((address_space(1))) void*)g,
      (__attribute__((address_space(3))) void*)l, 16, 0, 0);
}

// fp32 -> bf16, 8 elements per thread.
__global__ __launch_bounds__(256) void cvt_kernel(const float* __restrict__ src,
                                                  u16* __restrict__ dst) {
  const size_t i = ((size_t)blockIdx.x * 256 + threadIdx.x) * 8;
  float4 a = *(const float4*)(src + i);
  float4 b = *(const float4*)(src + i + 4);
  u16 t[8] = {f2b(a.x), f2b(a.y), f2b(a.z), f2b(a.w),
              f2b(b.x), f2b(b.y), f2b(b.z), f2b(b.w)};
  *(uint4*)(dst + i) = *(const uint4*)t;
}

// dst[n*K + k] = bf16(w[((n>>3)*I + (k>>3))*8 + ((n-k)&7)]); 8 k per thread.
// kshift = log2(K/8). Vectorized: 32B read, 16B write per thread.
__global__ __launch_bounds__(256) void expand_kernel(const float* __restrict__ w,
                                                     u16* __restrict__ dst,
                                                     int I, int kshift) {
  const int gid = blockIdx.x * 256 + threadIdx.x;
  const int n = gid >> kshift;
  const int kc = (gid & ((1 << kshift) - 1)) * 8;
  const int K = 8 << kshift;
  const float* wp = w + (size_t)((n >> 3) * I + (kc >> 3)) * 8;
  float4 w0 = *(const float4*)wp;
  float4 w1 = *(const float4*)(wp + 4);
  float w8[8] = {w0.x, w0.y, w0.z, w0.w, w1.x, w1.y, w1.z, w1.w};
  u16 t[8];
  const int r = (n - kc) & 7;
#pragma unroll
  for (int j = 0; j < 8; ++j) t[j] = f2b(w8[(r - j) & 7]);
  *(uint4*)(dst + (size_t)n * K + kc) = *(const uint4*)t;
}

// Y[m,n] = sum_k X[m,k]*W[n,k] + bias[n>>3] (+ res[m,n]); X,W bf16, accum fp32.
// XOR k-group swizzle on LDS layout to cut ds_read_b128 bank aliasing 8-way -> 4-way.
template <bool HAS_RES, bool OUT_F32>
__global__ __launch_bounds__(256) void gemm_bt(
    const u16* __restrict__ X, const u16* __restrict__ W,
    const float* __restrict__ bias, const float* __restrict__ res,
    void* __restrict__ Yv, int M, int N, int K) {
  __shared__ __align__(16) u16 As[TILE * BK];
  __shared__ __align__(16) u16 Bs[TILE * BK];
  const int tid = threadIdx.x;
  const int m0 = blockIdx.y * TILE;
  const int n0 = blockIdx.x * TILE;
  const int lane = tid & 63;
  const int wave = tid >> 6;
  const int wm = (wave >> 1) * 64;
  const int wn = (wave & 1) * 64;
  const int l16 = lane & 15;
  const int quad = lane >> 4;

  f32x4_t acc[4][4] = {};

  const int row0 = tid >> 2;                              // 0..63
  const int kg0 = ((tid & 3) ^ (row0 & 3)) * 8;           // swizzled k-group
  const int sw = (quad ^ (l16 & 3)) * 8;                  // matching read swizzle

  for (int k0 = 0; k0 < K; k0 += BK) {
#pragma unroll
    for (int it = 0; it < 2; ++it) {
      const int row = row0 + it * 64;
      const int cc = tid + it * 256;
      async_lds16(X + (size_t)(m0 + row) * K + (k0 + kg0), &As[cc * 8]);
      async_lds16(W + (size_t)(n0 + row) * K + (k0 + kg0), &Bs[cc * 8]);
    }
    __syncthreads();
    bf16x8_t af[4], bfr[4];
#pragma unroll
    for (int i = 0; i < 4; ++i)
      af[i] = *(const bf16x8_t*)&As[(wm + i * 16 + l16) * BK + sw];
#pragma unroll
    for (int j = 0; j < 4; ++j)
      bfr[j] = *(const bf16x8_t*)&Bs[(wn + j * 16 + l16) * BK + sw];
#pragma unroll
    for (int i = 0; i < 4; ++i)
#pragma unroll
      for (int j = 0; j < 4; ++j)
        acc[i][j] = __builtin_amdgcn_mfma_f32_16x16x32_bf16(af[i], bfr[j], acc[i][j], 0, 0, 0);
    __syncthreads();
  }

#pragma unroll
  for (int j = 0; j < 4; ++j) {
    const int col = n0 + wn + j * 16 + l16;
    const float bv = bias[col >> 3];
#pragma unroll
    for (int i = 0; i < 4; ++i) {
#pragma unroll
      for (int r = 0; r < 4; ++r) {
        const int rw = m0 + wm + i * 16 + quad * 4 + r;
        float vv = acc[i][j][r] + bv;
        if (HAS_RES) vv += res[(size_t)rw * N + col];
        if (OUT_F32)
          ((float*)Yv)[(size_t)rw * N + col] = vv;
        else
          ((u16*)Yv)[(size_t)rw * N + col] = f2b(vv);
      }
    }
  }
}

// One wave per (b,h) pair. qp/kp/vp: [B,4096] bf16, layout g*512+h*64+d.
// probs: fp32 out, 64 per pair ([b,h,qg,kg]). o: bf16 at g*512+h*64+d.
__global__ __launch_bounds__(256) void attn_kernel(
    const u16* __restrict__ qp, const u16* __restrict__ kp,
    const u16* __restrict__ vp, float* __restrict__ probs,
    u16* __restrict__ o) {
  __shared__ __align__(16) u16 Qs[4][8 * 72];
  __shared__ __align__(16) u16 Ks[4][8 * 72];
  __shared__ __align__(16) u16 Vs[4][8 * 72];
  __shared__ float Ps[4][64];
  const int tid = threadIdx.x;
  const int wave = tid >> 6;
  const int lane = tid & 63;
  const int pair = blockIdx.x * 4 + wave;
  const int b = pair >> 3;
  const int h = pair & 7;
  {
    const int r = lane >> 3, c = lane & 7;
    const size_t g = (size_t)b * 4096 + (size_t)r * 512 + h * 64 + c * 8;
    const int ls = r * 72 + c * 8;
    *(uint4*)&Qs[wave][ls] = *(const uint4*)(qp + g);
    *(uint4*)&Ks[wave][ls] = *(const uint4*)(kp + g);
    *(uint4*)&Vs[wave][ls] = *(const uint4*)(vp + g);
  }
  __syncthreads();
  const int qg = lane >> 3;
  const int kg = lane & 7;
  float s = 0.f;
#pragma unroll
  for (int d8 = 0; d8 < 8; ++d8) {
    uint4 qa = *(const uint4*)&Qs[wave][qg * 72 + d8 * 8];
    uint4 ka = *(const uint4*)&Ks[wave][kg * 72 + d8 * 8];
    s += blo(qa.x) * blo(ka.x) + bhi(qa.x) * bhi(ka.x);
    s += blo(qa.y) * blo(ka.y) + bhi(qa.y) * bhi(ka.y);
    s += blo(qa.z) * blo(ka.z) + bhi(qa.z) * bhi(ka.z);
    s += blo(qa.w) * blo(ka.w) + bhi(qa.w) * bhi(ka.w);
  }
  s *= 0.125f;  // 1/sqrt(dk)
  float mx = s;
  mx = fmaxf(mx, __shfl_xor(mx, 1));
  mx = fmaxf(mx, __shfl_xor(mx, 2));
  mx = fmaxf(mx, __shfl_xor(mx, 4));
  float e = __expf(s - mx);
  float sum = e;
  sum += __shfl_xor(sum, 1);
  sum += __shfl_xor(sum, 2);
  sum += __shfl_xor(sum, 4);
  const float p = e / sum;
  probs[(size_t)pair * 64 + lane] = p;
  Ps[wave][lane] = p;
  __syncthreads();
  float vc[8];
#pragma unroll
  for (int k2 = 0; k2 < 8; ++k2) vc[k2] = b2f(Vs[wave][k2 * 72 + lane]);
#pragma unroll
  for (int q2 = 0; q2 < 8; ++q2) {
    float acc = 0.f;
#pragma unroll
    for (int k2 = 0; k2 < 8; ++k2) acc += Ps[wave][q2 * 8 + k2] * vc[k2];
    o[(size_t)b * 4096 + q2 * 512 + h * 64 + lane] = f2b(acc);
  }
}

extern "C" void kernel_launch(void* const* d_in, const int* in_sizes, int n_in,
                              void* d_out, int out_size, void* d_ws, size_t ws_size,
                              hipStream_t stream) {
  const float* q = (const float*)d_in[0];
  const float* k = (const float*)d_in[1];
  const float* v = (const float*)d_in[2];
  const float* w_q = (const float*)d_in[3];
  const float* b_q = (const float*)d_in[4];
  const float* w_k = (const float*)d_in[5];
  const float* b_k = (const float*)d_in[6];
  const float* w_v = (const float*)d_in[7];
  const float* b_v = (const float*)d_in[8];
  const float* w_fc = (const float*)d_in[9];
  const float* b_fc = (const float*)d_in[10];

  const int B = in_sizes[0] / 1024;  // 8192
  float* out = (float*)d_out;                   // B*1024 fp32
  float* probs = out + (size_t)B * 1024;        // B*512 fp32 (attn)

  // workspace layout (all bf16 = u16)
  u16* Wq = (u16*)d_ws;
  u16* Wk = Wq + (size_t)4096 * 1024;
  u16* Wv = Wk + (size_t)4096 * 1024;
  u16* Wfc = Wv + (size_t)4096 * 1024;  // 1024x4096
  u16* scratch = Wfc + (size_t)4096 * 1024;
  const size_t wbytes = (size_t)4 * 4096 * 1024 * sizeof(u16);

  // per-row scratch: qb,kb,vb (1024 each) + qp,kp,vp,ao (4096 each), bf16
  const size_t per_row = (size_t)(3 * 1024 + 4 * 4096) * sizeof(u16);
  int chunkB = 128;
  for (int c = B; c >= 128; c >>= 1) {
    if (wbytes + (size_t)c * per_row <= ws_size) { chunkB = c; break; }
  }

  // expand circulant weights (fp32 -> bf16), 8 elems/thread
  expand_kernel<<<2048, 256, 0, stream>>>(w_q, Wq, 128, 7);
  expand_kernel<<<2048, 256, 0, stream>>>(w_k, Wk, 128, 7);
  expand_kernel<<<2048, 256, 0, stream>>>(w_v, Wv, 128, 7);
  expand_kernel<<<2048, 256, 0, stream>>>(w_fc, Wfc, 512, 9);

  u16* qb = scratch;
  u16* kb = qb + (size_t)chunkB * 1024;
  u16* vb = kb + (size_t)chunkB * 1024;
  u16* qp = vb + (size_t)chunkB * 1024;
  u16* kp = qp + (size_t)chunkB * 4096;
  u16* vp = kp + (size_t)chunkB * 4096;
  u16* ao = vp + (size_t)chunkB * 4096;

  for (int cs = 0; cs < B; cs += chunkB) {
    const int cvtBlocks = chunkB / 2;  // chunkB*1024 / 8 / 256
    cvt_kernel<<<cvtBlocks, 256, 0, stream>>>(q + (size_t)cs * 1024, qb);
    cvt_kernel<<<cvtBlocks, 256, 0, stream>>>(k + (size_t)cs * 1024, kb);
    cvt_kernel<<<cvtBlocks, 256, 0, stream>>>(v + (size_t)cs * 1024, vb);

    dim3 gp(4096 / TILE, chunkB / TILE);
    gemm_bt<false, false><<<gp, 256, 0, stream>>>(qb, Wq, b_q, nullptr, qp,
                                                  chunkB, 4096, 1024);
    gemm_bt<false, false><<<gp, 256, 0, stream>>>(kb, Wk, b_k, nullptr, kp,
                                                  chunkB, 4096, 1024);
    gemm_bt<false, false><<<gp, 256, 0, stream>>>(vb, Wv, b_v, nullptr, vp,
                                                  chunkB, 4096, 1024);
    attn_kernel<<<chunkB * 2, 256, 0, stream>>>(qp, kp, vp,
                                                probs + (size_t)cs * 512, ao);
    gemm_bt<true, true><<<dim3(1024 / TILE, chunkB / TILE), 256, 0, stream>>>(
        ao, Wfc, b_fc, q + (size_t)cs * 1024, out + (size_t)cs * 1024,
        chunkB, 1024, 4096);
  }
}

// Round 4
// 664.186 us; speedup vs baseline: 1.2269x; 1.1380x over previous
//
#include <hip/hip_runtime.h>
#include <hip/hip_bf16.h>

typedef unsigned short u16;
typedef unsigned int u32;
typedef __bf16 bf16x8_t __attribute__((ext_vector_type(8)));
typedef float f32x4_t __attribute__((ext_vector_type(4)));

#define TILE 128
#define BK 64

__device__ __forceinline__ float b2f(u16 v) {
  return __uint_as_float(((u32)v) << 16);
}
__device__ __forceinline__ u16 f2b(float f) {
  __hip_bfloat16 h = __float2bfloat16(f);
  return *reinterpret_cast<u16*>(&h);
}
__device__ __forceinline__ float blo(u32 u) { return __uint_as_float(u << 16); }
__device__ __forceinline__ float bhi(u32 u) { return __uint_as_float(u & 0xffff0000u); }

__device__ __forceinline__ void async_lds16(const u16* g, u16* l) {
  __builtin_amdgcn_global_load_lds(
      (__attribute__((address_space(1))) void*)g,
      (__attribute__((address_space(3))) void*)l, 16, 0, 0);
}

// fp32 -> bf16 for q,k,v in one dispatch (blockIdx.y selects tensor).
__global__ __launch_bounds__(256) void cvt_qkv_kernel(
    const float* __restrict__ q, const float* __restrict__ k,
    const float* __restrict__ v, u16* __restrict__ qb, u16* __restrict__ kb,
    u16* __restrict__ vb) {
  const float* src = (blockIdx.y == 0) ? q : (blockIdx.y == 1) ? k : v;
  u16* dst = (blockIdx.y == 0) ? qb : (blockIdx.y == 1) ? kb : vb;
  const size_t i = ((size_t)blockIdx.x * 256 + threadIdx.x) * 8;
  float4 a = *(const float4*)(src + i);
  float4 b = *(const float4*)(src + i + 4);
  u16 t[8] = {f2b(a.x), f2b(a.y), f2b(a.z), f2b(a.w),
              f2b(b.x), f2b(b.y), f2b(b.z), f2b(b.w)};
  *(uint4*)(dst + i) = *(const uint4*)t;
}

// dst[n*K + k] = bf16(w[((n>>3)*I + (k>>3))*8 + ((n-k)&7)]); 8 k per thread.
__global__ __launch_bounds__(256) void expand_kernel(const float* __restrict__ w,
                                                     u16* __restrict__ dst,
                                                     int I, int kshift) {
  const int gid = blockIdx.x * 256 + threadIdx.x;
  const int n = gid >> kshift;
  const int kc = (gid & ((1 << kshift) - 1)) * 8;
  const int K = 8 << kshift;
  const float* wp = w + (size_t)((n >> 3) * I + (kc >> 3)) * 8;
  float4 w0 = *(const float4*)wp;
  float4 w1 = *(const float4*)(wp + 4);
  float w8[8] = {w0.x, w0.y, w0.z, w0.w, w1.x, w1.y, w1.z, w1.w};
  u16 t[8];
  const int r = (n - kc) & 7;
#pragma unroll
  for (int j = 0; j < 8; ++j) t[j] = f2b(w8[(r - j) & 7]);
  *(uint4*)(dst + (size_t)n * K + kc) = *(const uint4*)t;
}

// Core: Y[m,n] = sum_k X[m,k]*W[n,k] + bias[n>>3] (+ res); bf16 in, fp32 accum.
// BK=64, XOR-8 k-block swizzle in LDS (conflict-free reads at 128B row stride),
// XCD-chunked + group-M swizzled 1D grid for L2 locality.
template <bool HAS_RES, bool OUT_F32>
__device__ __forceinline__ void gemm_core(
    const u16* __restrict__ X, const u16* __restrict__ W,
    const float* __restrict__ bias, const float* __restrict__ res,
    void* __restrict__ Yv, int M, int N, int K, int bid) {
  __shared__ __align__(16) u16 As[TILE * BK];
  __shared__ __align__(16) u16 Bs[TILE * BK];
  const int tid = threadIdx.x;

  // grid swizzle
  const int grid_m = M >> 7, grid_n = N >> 7;
  const int nb = grid_m * grid_n;
  int pid = (bid & 7) * (nb >> 3) + (bid >> 3);  // XCD-contiguous spans
  const int nig = 8 * grid_n;
  const int group_id = pid / nig;
  const int first_m = group_id * 8;
  const int gsz = min(8, grid_m - first_m);
  const int mt = first_m + (pid % gsz);
  const int nt = (pid % nig) / gsz;
  const int m0 = mt << 7, n0 = nt << 7;

  const int lane = tid & 63;
  const int wave = tid >> 6;
  const int wm = (wave >> 1) * 64;
  const int wn = (wave & 1) * 64;
  const int l16 = lane & 15;
  const int quad = lane >> 4;

  f32x4_t acc[4][4] = {};

  const int row0 = tid >> 3;                          // 0..31
  const int kgl = ((tid & 7) ^ (row0 & 7)) * 8;       // fetched global k-block

  for (int k0 = 0; k0 < K; k0 += BK) {
#pragma unroll
    for (int it = 0; it < 4; ++it) {
      const int row = row0 + it * 32;
      const int off = (tid + it * 256) * 8;
      async_lds16(X + (size_t)(m0 + row) * K + (k0 + kgl), &As[off]);
      async_lds16(W + (size_t)(n0 + row) * K + (k0 + kgl), &Bs[off]);
    }
    __syncthreads();
#pragma unroll
    for (int half = 0; half < 2; ++half) {
      bf16x8_t af[4], bfr[4];
#pragma unroll
      for (int i = 0; i < 4; ++i)
        af[i] = *(const bf16x8_t*)&As[(wm + i * 16 + l16) * BK +
                                      (((quad + half * 4) ^ (l16 & 7)) * 8)];
#pragma unroll
      for (int j = 0; j < 4; ++j)
        bfr[j] = *(const bf16x8_t*)&Bs[(wn + j * 16 + l16) * BK +
                                       (((quad + half * 4) ^ (l16 & 7)) * 8)];
#pragma unroll
      for (int i = 0; i < 4; ++i)
#pragma unroll
        for (int j = 0; j < 4; ++j)
          acc[i][j] =
              __builtin_amdgcn_mfma_f32_16x16x32_bf16(af[i], bfr[j], acc[i][j], 0, 0, 0);
    }
    __syncthreads();
  }

#pragma unroll
  for (int j = 0; j < 4; ++j) {
    const int col = n0 + wn + j * 16 + l16;
    const float bv = bias[col >> 3];
#pragma unroll
    for (int i = 0; i < 4; ++i) {
#pragma unroll
      for (int r = 0; r < 4; ++r) {
        const int rw = m0 + wm + i * 16 + quad * 4 + r;
        float vv = acc[i][j][r] + bv;
        if (HAS_RES) vv += res[(size_t)rw * N + col];
        if (OUT_F32)
          ((float*)Yv)[(size_t)rw * N + col] = vv;
        else
          ((u16*)Yv)[(size_t)rw * N + col] = f2b(vv);
      }
    }
  }
}

// q/k/v projections in one dispatch: blockIdx.y in {0,1,2}.
__global__ __launch_bounds__(256) void gemm_qkv(
    const u16* __restrict__ X0, const u16* __restrict__ X1,
    const u16* __restrict__ X2, const u16* __restrict__ W0,
    const u16* __restrict__ W1, const u16* __restrict__ W2,
    const float* __restrict__ b0, const float* __restrict__ b1,
    const float* __restrict__ b2, u16* __restrict__ Y0, u16* __restrict__ Y1,
    u16* __restrict__ Y2, int M, int N, int K) {
  const int z = blockIdx.y;
  const u16* X = (z == 0) ? X0 : (z == 1) ? X1 : X2;
  const u16* W = (z == 0) ? W0 : (z == 1) ? W1 : W2;
  const float* bb = (z == 0) ? b0 : (z == 1) ? b1 : b2;
  u16* Y = (z == 0) ? Y0 : (z == 1) ? Y1 : Y2;
  gemm_core<false, false>(X, W, bb, nullptr, Y, M, N, K, blockIdx.x);
}

__global__ __launch_bounds__(256) void gemm_fc(
    const u16* __restrict__ X, const u16* __restrict__ W,
    const float* __restrict__ bias, const float* __restrict__ res,
    float* __restrict__ Y, int M, int N, int K) {
  gemm_core<true, true>(X, W, bias, res, Y, M, N, K, blockIdx.x);
}

// One wave per (b,h) pair. qp/kp/vp: [B,4096] bf16, layout g*512+h*64+d.
// probs: fp32, 64 per pair ([b,h,qg,kg]). o: bf16 at g*512+h*64+d.
__global__ __launch_bounds__(256) void attn_kernel(
    const u16* __restrict__ qp, const u16* __restrict__ kp,
    const u16* __restrict__ vp, float* __restrict__ probs,
    u16* __restrict__ o) {
  __shared__ __align__(16) u16 Qs[4][8 * 72];
  __shared__ __align__(16) u16 Ks[4][8 * 72];
  __shared__ __align__(16) u16 Vs[4][8 * 72];
  __shared__ float Ps[4][64];
  const int tid = threadIdx.x;
  const int wave = tid >> 6;
  const int lane = tid & 63;
  const int pair = blockIdx.x * 4 + wave;
  const int b = pair >> 3;
  const int h = pair & 7;
  {
    const int r = lane >> 3, c = lane & 7;
    const size_t g = (size_t)b * 4096 + (size_t)r * 512 + h * 64 + c * 8;
    const int ls = r * 72 + c * 8;
    *(uint4*)&Qs[wave][ls] = *(const uint4*)(qp + g);
    *(uint4*)&Ks[wave][ls] = *(const uint4*)(kp + g);
    *(uint4*)&Vs[wave][ls] = *(const uint4*)(vp + g);
  }
  __syncthreads();
  const int qg = lane >> 3;
  const int kg = lane & 7;
  float s = 0.f;
#pragma unroll
  for (int d8 = 0; d8 < 8; ++d8) {
    uint4 qa = *(const uint4*)&Qs[wave][qg * 72 + d8 * 8];
    uint4 ka = *(const uint4*)&Ks[wave][kg * 72 + d8 * 8];
    s += blo(qa.x) * blo(ka.x) + bhi(qa.x) * bhi(ka.x);
    s += blo(qa.y) * blo(ka.y) + bhi(qa.y) * bhi(ka.y);
    s += blo(qa.z) * blo(ka.z) + bhi(qa.z) * bhi(ka.z);
    s += blo(qa.w) * blo(ka.w) + bhi(qa.w) * bhi(ka.w);
  }
  s *= 0.125f;  // 1/sqrt(dk)
  float mx = s;
  mx = fmaxf(mx, __shfl_xor(mx, 1));
  mx = fmaxf(mx, __shfl_xor(mx, 2));
  mx = fmaxf(mx, __shfl_xor(mx, 4));
  float e = __expf(s - mx);
  float sum = e;
  sum += __shfl_xor(sum, 1);
  sum += __shfl_xor(sum, 2);
  sum += __shfl_xor(sum, 4);
  const float p = e / sum;
  probs[(size_t)pair * 64 + lane] = p;
  Ps[wave][lane] = p;
  __syncthreads();
  float vc[8];
#pragma unroll
  for (int k2 = 0; k2 < 8; ++k2) vc[k2] = b2f(Vs[wave][k2 * 72 + lane]);
#pragma unroll
  for (int q2 = 0; q2 < 8; ++q2) {
    float acc = 0.f;
#pragma unroll
    for (int k2 = 0; k2 < 8; ++k2) acc += Ps[wave][q2 * 8 + k2] * vc[k2];
    o[(size_t)b * 4096 + q2 * 512 + h * 64 + lane] = f2b(acc);
  }
}

extern "C" void kernel_launch(void* const* d_in, const int* in_sizes, int n_in,
                              void* d_out, int out_size, void* d_ws, size_t ws_size,
                              hipStream_t stream) {
  const float* q = (const float*)d_in[0];
  const float* k = (const float*)d_in[1];
  const float* v = (const float*)d_in[2];
  const float* w_q = (const float*)d_in[3];
  const float* b_q = (const float*)d_in[4];
  const float* w_k = (const float*)d_in[5];
  const float* b_k = (const float*)d_in[6];
  const float* w_v = (const float*)d_in[7];
  const float* b_v = (const float*)d_in[8];
  const float* w_fc = (const float*)d_in[9];
  const float* b_fc = (const float*)d_in[10];

  const int B = in_sizes[0] / 1024;  // 8192
  float* out = (float*)d_out;                   // B*1024 fp32
  float* probs = out + (size_t)B * 1024;        // B*512 fp32 (attn)

  // workspace layout (all bf16 = u16)
  u16* Wq = (u16*)d_ws;
  u16* Wk = Wq + (size_t)4096 * 1024;
  u16* Wv = Wk + (size_t)4096 * 1024;
  u16* Wfc = Wv + (size_t)4096 * 1024;  // 1024x4096
  u16* scratch = Wfc + (size_t)4096 * 1024;
  const size_t wbytes = (size_t)4 * 4096 * 1024 * sizeof(u16);

  // per-row scratch: qb,kb,vb (1024 each) + qp,kp,vp,ao (4096 each), bf16
  const size_t per_row = (size_t)(3 * 1024 + 4 * 4096) * sizeof(u16);
  int chunkB = 128;
  for (int c = B; c >= 128; c >>= 1) {
    if (wbytes + (size_t)c * per_row <= ws_size) { chunkB = c; break; }
  }

  // expand circulant weights (fp32 -> bf16), 8 elems/thread
  expand_kernel<<<2048, 256, 0, stream>>>(w_q, Wq, 128, 7);
  expand_kernel<<<2048, 256, 0, stream>>>(w_k, Wk, 128, 7);
  expand_kernel<<<2048, 256, 0, stream>>>(w_v, Wv, 128, 7);
  expand_kernel<<<2048, 256, 0, stream>>>(w_fc, Wfc, 512, 9);

  u16* qb = scratch;
  u16* kb = qb + (size_t)chunkB * 1024;
  u16* vb = kb + (size_t)chunkB * 1024;
  u16* qp = vb + (size_t)chunkB * 1024;
  u16* kp = qp + (size_t)chunkB * 4096;
  u16* vp = kp + (size_t)chunkB * 4096;
  u16* ao = vp + (size_t)chunkB * 4096;

  for (int cs = 0; cs < B; cs += chunkB) {
    cvt_qkv_kernel<<<dim3(chunkB / 2, 3), 256, 0, stream>>>(
        q + (size_t)cs * 1024, k + (size_t)cs * 1024, v + (size_t)cs * 1024,
        qb, kb, vb);

    const int nb_p = (chunkB / TILE) * (4096 / TILE);
    gemm_qkv<<<dim3(nb_p, 3), 256, 0, stream>>>(qb, kb, vb, Wq, Wk, Wv, b_q,
                                                b_k, b_v, qp, kp, vp, chunkB,
                                                4096, 1024);
    attn_kernel<<<chunkB * 2, 256, 0, stream>>>(qp, kp, vp,
                                                probs + (size_t)cs * 512, ao);
    const int nb_fc = (chunkB / TILE) * (1024 / TILE);
    gemm_fc<<<nb_fc, 256, 0, stream>>>(ao, Wfc, b_fc, q + (size_t)cs * 1024,
                                       out + (size_t)cs * 1024, chunkB, 1024,
                                       4096);
  }
}

// Round 5
// 658.866 us; speedup vs baseline: 1.2368x; 1.0081x over previous
//
#include <hip/hip_runtime.h>
#include <hip/hip_bf16.h>

typedef unsigned short u16;
typedef unsigned int u32;
typedef __bf16 bf16x8_t __attribute__((ext_vector_type(8)));
typedef float f32x4_t __attribute__((ext_vector_type(4)));

#define TILE 128
#define BK 64

__device__ __forceinline__ float b2f(u16 v) {
  return __uint_as_float(((u32)v) << 16);
}
__device__ __forceinline__ u16 f2b(float f) {
  __hip_bfloat16 h = __float2bfloat16(f);
  return *reinterpret_cast<u16*>(&h);
}
__device__ __forceinline__ float blo(u32 u) { return __uint_as_float(u << 16); }
__device__ __forceinline__ float bhi(u32 u) { return __uint_as_float(u & 0xffff0000u); }

__device__ __forceinline__ void async_lds16(const u16* g, u16* l) {
  __builtin_amdgcn_global_load_lds(
      (__attribute__((address_space(1))) void*)g,
      (__attribute__((address_space(3))) void*)l, 16, 0, 0);
}

__device__ __forceinline__ void cvt8(const float* __restrict__ src,
                                     u16* __restrict__ dst, size_t i) {
  float4 a = *(const float4*)(src + i);
  float4 b = *(const float4*)(src + i + 4);
  u16 t[8] = {f2b(a.x), f2b(a.y), f2b(a.z), f2b(a.w),
              f2b(b.x), f2b(b.y), f2b(b.z), f2b(b.w)};
  *(uint4*)(dst + i) = *(const uint4*)t;
}

__device__ __forceinline__ void expand8(const float* __restrict__ w,
                                        u16* __restrict__ dst, int I,
                                        int kshift, int gid) {
  const int n = gid >> kshift;
  const int kc = (gid & ((1 << kshift) - 1)) * 8;
  const int K = 8 << kshift;
  const float* wp = w + (size_t)((n >> 3) * I + (kc >> 3)) * 8;
  float4 w0 = *(const float4*)wp;
  float4 w1 = *(const float4*)(wp + 4);
  float w8[8] = {w0.x, w0.y, w0.z, w0.w, w1.x, w1.y, w1.z, w1.w};
  u16 t[8];
  const int r = (n - kc) & 7;
#pragma unroll
  for (int j = 0; j < 8; ++j) t[j] = f2b(w8[(r - j) & 7]);
  *(uint4*)(dst + (size_t)n * K + kc) = *(const uint4*)t;
}

// One dispatch for all prep work. Plane ranges over blockIdx.x:
// [0,C): cvt q | [C,2C): cvt k | [2C,3C): cvt v
// then (if expand) 2048 blocks each for Wq, Wk, Wv, Wfc.
__global__ __launch_bounds__(256) void prep_kernel(
    const float* __restrict__ q, const float* __restrict__ k,
    const float* __restrict__ v, u16* __restrict__ qb, u16* __restrict__ kb,
    u16* __restrict__ vb, const float* __restrict__ w_q,
    const float* __restrict__ w_k, const float* __restrict__ w_v,
    const float* __restrict__ w_fc, u16* __restrict__ Wq, u16* __restrict__ Wk,
    u16* __restrict__ Wv, u16* __restrict__ Wfc, int C) {
  const int bid = blockIdx.x;
  const int tid = threadIdx.x;
  if (bid < 3 * C) {
    const int plane = bid / C;
    const int b2 = bid - plane * C;
    const float* src = (plane == 0) ? q : (plane == 1) ? k : v;
    u16* dst = (plane == 0) ? qb : (plane == 1) ? kb : vb;
    cvt8(src, dst, ((size_t)b2 * 256 + tid) * 8);
  } else {
    const int e = bid - 3 * C;
    const int plane = e >> 11;         // 2048 blocks per weight
    const int gid = (e & 2047) * 256 + tid;
    if (plane == 0) expand8(w_q, Wq, 128, 7, gid);
    else if (plane == 1) expand8(w_k, Wk, 128, 7, gid);
    else if (plane == 2) expand8(w_v, Wv, 128, 7, gid);
    else expand8(w_fc, Wfc, 512, 9, gid);
  }
}

// Core: Y[m,n] = sum_k X[m,k]*W[n,k] + bias[n>>3] (+ res); bf16 in, fp32 accum.
// BK=64, XOR-8 k-block swizzle, XCD-chunked + group-M swizzled 1D grid.
template <bool HAS_RES, bool OUT_F32>
__device__ __forceinline__ void gemm_core(
    const u16* __restrict__ X, const u16* __restrict__ W,
    const float* __restrict__ bias, const float* __restrict__ res,
    void* __restrict__ Yv, int M, int N, int K, int bid) {
  __shared__ __align__(16) u16 As[TILE * BK];
  __shared__ __align__(16) u16 Bs[TILE * BK];
  const int tid = threadIdx.x;

  const int grid_m = M >> 7, grid_n = N >> 7;
  const int nb = grid_m * grid_n;
  int pid = (bid & 7) * (nb >> 3) + (bid >> 3);
  const int nig = 8 * grid_n;
  const int group_id = pid / nig;
  const int first_m = group_id * 8;
  const int gsz = min(8, grid_m - first_m);
  const int mt = first_m + (pid % gsz);
  const int nt = (pid % nig) / gsz;
  const int m0 = mt << 7, n0 = nt << 7;

  const int lane = tid & 63;
  const int wave = tid >> 6;
  const int wm = (wave >> 1) * 64;
  const int wn = (wave & 1) * 64;
  const int l16 = lane & 15;
  const int quad = lane >> 4;

  f32x4_t acc[4][4] = {};

  const int row0 = tid >> 3;
  const int kgl = ((tid & 7) ^ (row0 & 7)) * 8;

  for (int k0 = 0; k0 < K; k0 += BK) {
#pragma unroll
    for (int it = 0; it < 4; ++it) {
      const int row = row0 + it * 32;
      const int off = (tid + it * 256) * 8;
      async_lds16(X + (size_t)(m0 + row) * K + (k0 + kgl), &As[off]);
      async_lds16(W + (size_t)(n0 + row) * K + (k0 + kgl), &Bs[off]);
    }
    __syncthreads();
#pragma unroll
    for (int half = 0; half < 2; ++half) {
      bf16x8_t af[4], bfr[4];
#pragma unroll
      for (int i = 0; i < 4; ++i)
        af[i] = *(const bf16x8_t*)&As[(wm + i * 16 + l16) * BK +
                                      (((quad + half * 4) ^ (l16 & 7)) * 8)];
#pragma unroll
      for (int j = 0; j < 4; ++j)
        bfr[j] = *(const bf16x8_t*)&Bs[(wn + j * 16 + l16) * BK +
                                       (((quad + half * 4) ^ (l16 & 7)) * 8)];
#pragma unroll
      for (int i = 0; i < 4; ++i)
#pragma unroll
        for (int j = 0; j < 4; ++j)
          acc[i][j] =
              __builtin_amdgcn_mfma_f32_16x16x32_bf16(af[i], bfr[j], acc[i][j], 0, 0, 0);
    }
    __syncthreads();
  }

#pragma unroll
  for (int j = 0; j < 4; ++j) {
    const int col = n0 + wn + j * 16 + l16;
    const float bv = bias[col >> 3];
#pragma unroll
    for (int i = 0; i < 4; ++i) {
#pragma unroll
      for (int r = 0; r < 4; ++r) {
        const int rw = m0 + wm + i * 16 + quad * 4 + r;
        float vv = acc[i][j][r] + bv;
        if (HAS_RES) vv += res[(size_t)rw * N + col];
        if (OUT_F32)
          ((float*)Yv)[(size_t)rw * N + col] = vv;
        else
          ((u16*)Yv)[(size_t)rw * N + col] = f2b(vv);
      }
    }
  }
}

__global__ __launch_bounds__(256) void gemm_qkv(
    const u16* __restrict__ X0, const u16* __restrict__ X1,
    const u16* __restrict__ X2, const u16* __restrict__ W0,
    const u16* __restrict__ W1, const u16* __restrict__ W2,
    const float* __restrict__ b0, const float* __restrict__ b1,
    const float* __restrict__ b2, u16* __restrict__ Y0, u16* __restrict__ Y1,
    u16* __restrict__ Y2, int M, int N, int K) {
  const int z = blockIdx.y;
  const u16* X = (z == 0) ? X0 : (z == 1) ? X1 : X2;
  const u16* W = (z == 0) ? W0 : (z == 1) ? W1 : W2;
  const float* bb = (z == 0) ? b0 : (z == 1) ? b1 : b2;
  u16* Y = (z == 0) ? Y0 : (z == 1) ? Y1 : Y2;
  gemm_core<false, false>(X, W, bb, nullptr, Y, M, N, K, blockIdx.x);
}

__global__ __launch_bounds__(256) void gemm_fc(
    const u16* __restrict__ X, const u16* __restrict__ W,
    const float* __restrict__ bias, const float* __restrict__ res,
    float* __restrict__ Y, int M, int N, int K) {
  gemm_core<true, true>(X, W, bias, res, Y, M, N, K, blockIdx.x);
}

// One wave per (b,h) pair, grid-stride over `iters` pairs/wave, software-
// pipelined loads, NO barriers (all LDS is wave-private).
__global__ __launch_bounds__(256) void attn_kernel(
    const u16* __restrict__ qp, const u16* __restrict__ kp,
    const u16* __restrict__ vp, float* __restrict__ probs,
    u16* __restrict__ o, int iters) {
  __shared__ __align__(16) u16 Qs[4][8 * 72];
  __shared__ __align__(16) u16 Ks[4][8 * 72];
  __shared__ __align__(16) u16 Vs[4][8 * 72];
  __shared__ float Ps[4][64];
  const int tid = threadIdx.x;
  const int wave = tid >> 6;
  const int lane = tid & 63;
  const int r = lane >> 3, c = lane & 7;
  const int ls = r * 72 + c * 8;
  const int qg = lane >> 3;
  const int kg = lane & 7;

  auto gaddr = [&](int it) {
    const int pair = (it * gridDim.x + blockIdx.x) * 4 + wave;
    return (size_t)(pair >> 3) * 4096 + (size_t)r * 512 + (pair & 7) * 64 + c * 8;
  };

  uint4 qr = *(const uint4*)(qp + gaddr(0));
  uint4 kr = *(const uint4*)(kp + gaddr(0));
  uint4 vr = *(const uint4*)(vp + gaddr(0));

  for (int it = 0; it < iters; ++it) {
    *(uint4*)&Qs[wave][ls] = qr;
    *(uint4*)&Ks[wave][ls] = kr;
    *(uint4*)&Vs[wave][ls] = vr;
    if (it + 1 < iters) {
      qr = *(const uint4*)(qp + gaddr(it + 1));
      kr = *(const uint4*)(kp + gaddr(it + 1));
      vr = *(const uint4*)(vp + gaddr(it + 1));
    }
    const int pair = (it * gridDim.x + blockIdx.x) * 4 + wave;
    const int b = pair >> 3;
    const int h = pair & 7;
    float s = 0.f;
#pragma unroll
    for (int d8 = 0; d8 < 8; ++d8) {
      uint4 qa = *(const uint4*)&Qs[wave][qg * 72 + d8 * 8];
      uint4 ka = *(const uint4*)&Ks[wave][kg * 72 + d8 * 8];
      s += blo(qa.x) * blo(ka.x) + bhi(qa.x) * bhi(ka.x);
      s += blo(qa.y) * blo(ka.y) + bhi(qa.y) * bhi(ka.y);
      s += blo(qa.z) * blo(ka.z) + bhi(qa.z) * bhi(ka.z);
      s += blo(qa.w) * blo(ka.w) + bhi(qa.w) * bhi(ka.w);
    }
    s *= 0.125f;  // 1/sqrt(dk)
    float mx = s;
    mx = fmaxf(mx, __shfl_xor(mx, 1));
    mx = fmaxf(mx, __shfl_xor(mx, 2));
    mx = fmaxf(mx, __shfl_xor(mx, 4));
    float e = __expf(s - mx);
    float sum = e;
    sum += __shfl_xor(sum, 1);
    sum += __shfl_xor(sum, 2);
    sum += __shfl_xor(sum, 4);
    const float p = e / sum;
    probs[(size_t)pair * 64 + lane] = p;
    Ps[wave][lane] = p;  // wave-private: no barrier needed
    float vc[8];
#pragma unroll
    for (int k2 = 0; k2 < 8; ++k2) vc[k2] = b2f(Vs[wave][k2 * 72 + lane]);
#pragma unroll
    for (int q2 = 0; q2 < 8; ++q2) {
      float acc = 0.f;
#pragma unroll
      for (int k2 = 0; k2 < 8; ++k2) acc += Ps[wave][q2 * 8 + k2] * vc[k2];
      o[(size_t)b * 4096 + q2 * 512 + h * 64 + lane] = f2b(acc);
    }
  }
}

extern "C" void kernel_launch(void* const* d_in, const int* in_sizes, int n_in,
                              void* d_out, int out_size, void* d_ws, size_t ws_size,
                              hipStream_t stream) {
  const float* q = (const float*)d_in[0];
  const float* k = (const float*)d_in[1];
  const float* v = (const float*)d_in[2];
  const float* w_q = (const float*)d_in[3];
  const float* b_q = (const float*)d_in[4];
  const float* w_k = (const float*)d_in[5];
  const float* b_k = (const float*)d_in[6];
  const float* w_v = (const float*)d_in[7];
  const float* b_v = (const float*)d_in[8];
  const float* w_fc = (const float*)d_in[9];
  const float* b_fc = (const float*)d_in[10];

  const int B = in_sizes[0] / 1024;  // 8192
  float* out = (float*)d_out;                   // B*1024 fp32
  float* probs = out + (size_t)B * 1024;        // B*512 fp32 (attn)

  u16* Wq = (u16*)d_ws;
  u16* Wk = Wq + (size_t)4096 * 1024;
  u16* Wv = Wk + (size_t)4096 * 1024;
  u16* Wfc = Wv + (size_t)4096 * 1024;  // 1024x4096
  u16* scratch = Wfc + (size_t)4096 * 1024;
  const size_t wbytes = (size_t)4 * 4096 * 1024 * sizeof(u16);

  const size_t per_row = (size_t)(3 * 1024 + 4 * 4096) * sizeof(u16);
  int chunkB = 128;
  for (int c = B; c >= 128; c >>= 1) {
    if (wbytes + (size_t)c * per_row <= ws_size) { chunkB = c; break; }
  }

  u16* qb = scratch;
  u16* kb = qb + (size_t)chunkB * 1024;
  u16* vb = kb + (size_t)chunkB * 1024;
  u16* qp = vb + (size_t)chunkB * 1024;
  u16* kp = qp + (size_t)chunkB * 4096;
  u16* vp = kp + (size_t)chunkB * 4096;
  u16* ao = vp + (size_t)chunkB * 4096;

  for (int cs = 0; cs < B; cs += chunkB) {
    const int C = chunkB / 2;  // cvt blocks per tensor
    const int prepBlocks = 3 * C + (cs == 0 ? 4 * 2048 : 0);
    prep_kernel<<<prepBlocks, 256, 0, stream>>>(
        q + (size_t)cs * 1024, k + (size_t)cs * 1024, v + (size_t)cs * 1024,
        qb, kb, vb, w_q, w_k, w_v, w_fc, Wq, Wk, Wv, Wfc, C);

    const int nb_p = (chunkB / TILE) * (4096 / TILE);
    gemm_qkv<<<dim3(nb_p, 3), 256, 0, stream>>>(qb, kb, vb, Wq, Wk, Wv, b_q,
                                                b_k, b_v, qp, kp, vp, chunkB,
                                                4096, 1024);
    const int ablocks = (chunkB >= 1024) ? 2048 : chunkB * 2;
    const int aiters = (chunkB * 8) / (ablocks * 4);
    attn_kernel<<<ablocks, 256, 0, stream>>>(qp, kp, vp,
                                             probs + (size_t)cs * 512, ao, aiters);
    const int nb_fc = (chunkB / TILE) * (1024 / TILE);
    gemm_fc<<<nb_fc, 256, 0, stream>>>(ao, Wfc, b_fc, q + (size_t)cs * 1024,
                                       out + (size_t)cs * 1024, chunkB, 1024,
                                       4096);
  }
}

// Round 6
// 605.498 us; speedup vs baseline: 1.3458x; 1.0881x over previous
//
#include <hip/hip_runtime.h>
#include <hip/hip_bf16.h>

typedef unsigned short u16;
typedef unsigned int u32;
typedef __bf16 bf16x8_t __attribute__((ext_vector_type(8)));
typedef float f32x4_t __attribute__((ext_vector_type(4)));

#define BK 64

__device__ __forceinline__ float b2f(u16 v) {
  return __uint_as_float(((u32)v) << 16);
}
__device__ __forceinline__ u16 f2b(float f) {
  __hip_bfloat16 h = __float2bfloat16(f);
  return *reinterpret_cast<u16*>(&h);
}
__device__ __forceinline__ float blo(u32 u) { return __uint_as_float(u << 16); }
__device__ __forceinline__ float bhi(u32 u) { return __uint_as_float(u & 0xffff0000u); }

__device__ __forceinline__ void async_lds16(const u16* g, u16* l) {
  __builtin_amdgcn_global_load_lds(
      (__attribute__((address_space(1))) void*)g,
      (__attribute__((address_space(3))) void*)l, 16, 0, 0);
}

__device__ __forceinline__ void expand8(const float* __restrict__ w,
                                        u16* __restrict__ dst, int I,
                                        int kshift, int gid) {
  const int n = gid >> kshift;
  const int kc = (gid & ((1 << kshift) - 1)) * 8;
  const int K = 8 << kshift;
  const float* wp = w + (size_t)((n >> 3) * I + (kc >> 3)) * 8;
  float4 w0 = *(const float4*)wp;
  float4 w1 = *(const float4*)(wp + 4);
  float w8[8] = {w0.x, w0.y, w0.z, w0.w, w1.x, w1.y, w1.z, w1.w};
  u16 t[8];
  const int r = (n - kc) & 7;
#pragma unroll
  for (int j = 0; j < 8; ++j) t[j] = f2b(w8[(r - j) & 7]);
  *(uint4*)(dst + (size_t)n * K + kc) = *(const uint4*)t;
}

// 2048 blocks per weight, 4 weights = 8192 blocks.
__global__ __launch_bounds__(256) void expand_all(
    const float* __restrict__ w_q, const float* __restrict__ w_k,
    const float* __restrict__ w_v, const float* __restrict__ w_fc,
    u16* __restrict__ Wq, u16* __restrict__ Wk, u16* __restrict__ Wv,
    u16* __restrict__ Wfc) {
  const int e = blockIdx.x;
  const int plane = e >> 11;
  const int gid = (e & 2047) * 256 + threadIdx.x;
  if (plane == 0) expand8(w_q, Wq, 128, 7, gid);
  else if (plane == 1) expand8(w_k, Wk, 128, 7, gid);
  else if (plane == 2) expand8(w_v, Wv, 128, 7, gid);
  else expand8(w_fc, Wfc, 512, 9, gid);
}

// Y[m,n] = sum_k X[m,k]*W[n,k] + bias[n>>3] (+ res); fp32 accum.
// TILE_M=128, TILE_N=TN (128 or 64). A either fp32 (converted in staging) or bf16.
// BK=64, XOR-8 k-block swizzle (conflict-free reads), XCD-chunked grid swizzle.
template <int TN, bool HAS_RES, bool OUT_F32, bool A_F32>
__device__ __forceinline__ void gemm_core(
    const void* __restrict__ Xv, const u16* __restrict__ W,
    const float* __restrict__ bias, const float* __restrict__ res,
    void* __restrict__ Yv, int M, int N, int K, int bid) {
  __shared__ __align__(16) u16 As[128 * BK];
  __shared__ __align__(16) u16 Bs[TN * BK];
  const int tid = threadIdx.x;

  const int grid_m = M >> 7, grid_n = N / TN;
  const int nb = grid_m * grid_n;
  int pid = (bid & 7) * (nb >> 3) + (bid >> 3);
  const int nig = 8 * grid_n;
  const int group_id = pid / nig;
  const int first_m = group_id * 8;
  const int gsz = min(8, grid_m - first_m);
  const int mt = first_m + (pid % gsz);
  const int nt = (pid % nig) / gsz;
  const int m0 = mt << 7, n0 = nt * TN;

  const int lane = tid & 63;
  const int wave = tid >> 6;
  const int wm = (wave >> 1) * 64;
  const int wn = (wave & 1) * (TN / 2);
  const int l16 = lane & 15;
  const int quad = lane >> 4;
  constexpr int NJ = TN >> 5;  // acc cols per wave

  f32x4_t acc[4][NJ] = {};

  const int row0 = tid >> 3;                     // 0..31
  const int kgl = ((tid & 7) ^ (row0 & 7)) * 8;  // swizzled k-block

  for (int k0 = 0; k0 < K; k0 += BK) {
    // B staging: async bf16
#pragma unroll
    for (int it = 0; it < TN / 32; ++it)
      async_lds16(W + (size_t)(n0 + row0 + it * 32) * K + (k0 + kgl),
                  &Bs[(tid + it * 256) * 8]);
    // A staging
    if (A_F32) {
      const float* Xf = (const float*)Xv;
      float4 fa[4], fb[4];
#pragma unroll
      for (int it = 0; it < 4; ++it) {
        const float* p = Xf + (size_t)(m0 + row0 + it * 32) * K + (k0 + kgl);
        fa[it] = *(const float4*)p;
        fb[it] = *(const float4*)(p + 4);
      }
#pragma unroll
      for (int it = 0; it < 4; ++it) {
        u16 t[8] = {f2b(fa[it].x), f2b(fa[it].y), f2b(fa[it].z), f2b(fa[it].w),
                    f2b(fb[it].x), f2b(fb[it].y), f2b(fb[it].z), f2b(fb[it].w)};
        *(uint4*)&As[(tid + it * 256) * 8] = *(const uint4*)t;
      }
    } else {
      const u16* Xb = (const u16*)Xv;
#pragma unroll
      for (int it = 0; it < 4; ++it)
        async_lds16(Xb + (size_t)(m0 + row0 + it * 32) * K + (k0 + kgl),
                    &As[(tid + it * 256) * 8]);
    }
    __syncthreads();
#pragma unroll
    for (int half = 0; half < 2; ++half) {
      bf16x8_t af[4], bfr[NJ];
#pragma unroll
      for (int i = 0; i < 4; ++i)
        af[i] = *(const bf16x8_t*)&As[(wm + i * 16 + l16) * BK +
                                      (((quad + half * 4) ^ (l16 & 7)) * 8)];
#pragma unroll
      for (int j = 0; j < NJ; ++j)
        bfr[j] = *(const bf16x8_t*)&Bs[(wn + j * 16 + l16) * BK +
                                       (((quad + half * 4) ^ (l16 & 7)) * 8)];
#pragma unroll
      for (int i = 0; i < 4; ++i)
#pragma unroll
        for (int j = 0; j < NJ; ++j)
          acc[i][j] =
              __builtin_amdgcn_mfma_f32_16x16x32_bf16(af[i], bfr[j], acc[i][j], 0, 0, 0);
    }
    __syncthreads();
  }

#pragma unroll
  for (int j = 0; j < NJ; ++j) {
    const int col = n0 + wn + j * 16 + l16;
    const float bv = bias[col >> 3];
#pragma unroll
    for (int i = 0; i < 4; ++i) {
#pragma unroll
      for (int r = 0; r < 4; ++r) {
        const int rw = m0 + wm + i * 16 + quad * 4 + r;
        float vv = acc[i][j][r] + bv;
        if (HAS_RES) vv += res[(size_t)rw * N + col];
        if (OUT_F32)
          ((float*)Yv)[(size_t)rw * N + col] = vv;
        else
          ((u16*)Yv)[(size_t)rw * N + col] = f2b(vv);
      }
    }
  }
}

// q/k/v projections, fp32 inputs converted inline. blockIdx.y in {0,1,2}.
__global__ __launch_bounds__(256) void gemm_qkv(
    const float* __restrict__ X0, const float* __restrict__ X1,
    const float* __restrict__ X2, const u16* __restrict__ W0,
    const u16* __restrict__ W1, const u16* __restrict__ W2,
    const float* __restrict__ b0, const float* __restrict__ b1,
    const float* __restrict__ b2, u16* __restrict__ Y0, u16* __restrict__ Y1,
    u16* __restrict__ Y2, int M, int N, int K) {
  const int z = blockIdx.y;
  const float* X = (z == 0) ? X0 : (z == 1) ? X1 : X2;
  const u16* W = (z == 0) ? W0 : (z == 1) ? W1 : W2;
  const float* bb = (z == 0) ? b0 : (z == 1) ? b1 : b2;
  u16* Y = (z == 0) ? Y0 : (z == 1) ? Y1 : Y2;
  gemm_core<128, false, false, true>(X, W, bb, nullptr, Y, M, N, K, blockIdx.x);
}

// fc: bf16 A (attn output), fp32 residual + fp32 output, TILE_N=64.
__global__ __launch_bounds__(256) void gemm_fc(
    const u16* __restrict__ X, const u16* __restrict__ W,
    const float* __restrict__ bias, const float* __restrict__ res,
    float* __restrict__ Y, int M, int N, int K) {
  gemm_core<64, true, true, false>(X, W, bias, res, Y, M, N, K, blockIdx.x);
}

// One wave per (b,h) pair, grid-stride `iters` pairs/wave, no barriers
// (wave-private LDS). V read direct from global (lane-coalesced rows).
__global__ __launch_bounds__(256) void attn_kernel(
    const u16* __restrict__ qp, const u16* __restrict__ kp,
    const u16* __restrict__ vp, float* __restrict__ probs,
    u16* __restrict__ o, int iters) {
  __shared__ __align__(16) u16 Qs[4][8 * 72];
  __shared__ __align__(16) u16 Ks[4][8 * 72];
  __shared__ __align__(16) float Ps[4][64];
  const int tid = threadIdx.x;
  const int wave = tid >> 6;
  const int lane = tid & 63;
  const int r = lane >> 3, c = lane & 7;
  const int ls = r * 72 + c * 8;
  const int qg = r;
  const int kg = c;

  auto pairof = [&](int it) { return (it * gridDim.x + blockIdx.x) * 4 + wave; };
  auto gaddr = [&](int it) {
    const int pr = pairof(it);
    return (size_t)(pr >> 3) * 4096 + (size_t)r * 512 + (pr & 7) * 64 + c * 8;
  };

  uint4 qr = *(const uint4*)(qp + gaddr(0));
  uint4 kr = *(const uint4*)(kp + gaddr(0));

  for (int it = 0; it < iters; ++it) {
    *(uint4*)&Qs[wave][ls] = qr;
    *(uint4*)&Ks[wave][ls] = kr;
    const int pair = pairof(it);
    const int b = pair >> 3;
    const int h = pair & 7;
    // V direct: per k2, 64 lanes read 128B contiguous.
    float vcf[8];
#pragma unroll
    for (int k2 = 0; k2 < 8; ++k2)
      vcf[k2] = b2f(vp[(size_t)b * 4096 + (size_t)k2 * 512 + h * 64 + lane]);
    if (it + 1 < iters) {
      qr = *(const uint4*)(qp + gaddr(it + 1));
      kr = *(const uint4*)(kp + gaddr(it + 1));
    }
    float s = 0.f;
#pragma unroll
    for (int d8 = 0; d8 < 8; ++d8) {
      uint4 qa = *(const uint4*)&Qs[wave][qg * 72 + d8 * 8];
      uint4 ka = *(const uint4*)&Ks[wave][kg * 72 + d8 * 8];
      s += blo(qa.x) * blo(ka.x) + bhi(qa.x) * bhi(ka.x);
      s += blo(qa.y) * blo(ka.y) + bhi(qa.y) * bhi(ka.y);
      s += blo(qa.z) * blo(ka.z) + bhi(qa.z) * bhi(ka.z);
      s += blo(qa.w) * blo(ka.w) + bhi(qa.w) * bhi(ka.w);
    }
    s *= 0.125f;  // 1/sqrt(dk)
    float mx = s;
    mx = fmaxf(mx, __shfl_xor(mx, 1));
    mx = fmaxf(mx, __shfl_xor(mx, 2));
    mx = fmaxf(mx, __shfl_xor(mx, 4));
    float e = __expf(s - mx);
    float sum = e;
    sum += __shfl_xor(sum, 1);
    sum += __shfl_xor(sum, 2);
    sum += __shfl_xor(sum, 4);
    const float p = e / sum;
    probs[(size_t)pair * 64 + lane] = p;
    Ps[wave][lane] = p;  // wave-private, lockstep: no barrier
#pragma unroll
    for (int q2 = 0; q2 < 8; ++q2) {
      float4 p0 = *(const float4*)&Ps[wave][q2 * 8];      // broadcast reads
      float4 p1 = *(const float4*)&Ps[wave][q2 * 8 + 4];
      float acc = p0.x * vcf[0] + p0.y * vcf[1] + p0.z * vcf[2] + p0.w * vcf[3] +
                  p1.x * vcf[4] + p1.y * vcf[5] + p1.z * vcf[6] + p1.w * vcf[7];
      o[(size_t)b * 4096 + q2 * 512 + h * 64 + lane] = f2b(acc);
    }
  }
}

extern "C" void kernel_launch(void* const* d_in, const int* in_sizes, int n_in,
                              void* d_out, int out_size, void* d_ws, size_t ws_size,
                              hipStream_t stream) {
  const float* q = (const float*)d_in[0];
  const float* k = (const float*)d_in[1];
  const float* v = (const float*)d_in[2];
  const float* w_q = (const float*)d_in[3];
  const float* b_q = (const float*)d_in[4];
  const float* w_k = (const float*)d_in[5];
  const float* b_k = (const float*)d_in[6];
  const float* w_v = (const float*)d_in[7];
  const float* b_v = (const float*)d_in[8];
  const float* w_fc = (const float*)d_in[9];
  const float* b_fc = (const float*)d_in[10];

  const int B = in_sizes[0] / 1024;  // 8192
  float* out = (float*)d_out;                   // B*1024 fp32
  float* probs = out + (size_t)B * 1024;        // B*512 fp32 (attn)

  u16* Wq = (u16*)d_ws;
  u16* Wk = Wq + (size_t)4096 * 1024;
  u16* Wv = Wk + (size_t)4096 * 1024;
  u16* Wfc = Wv + (size_t)4096 * 1024;  // 1024x4096
  u16* scratch = Wfc + (size_t)4096 * 1024;
  const size_t wbytes = (size_t)4 * 4096 * 1024 * sizeof(u16);

  // per-row scratch: qp,kp,vp,ao (4096 each), bf16
  const size_t per_row = (size_t)(4 * 4096) * sizeof(u16);
  int chunkB = 128;
  for (int c = B; c >= 128; c >>= 1) {
    if (wbytes + (size_t)c * per_row <= ws_size) { chunkB = c; break; }
  }

  u16* qp = scratch;
  u16* kp = qp + (size_t)chunkB * 4096;
  u16* vp = kp + (size_t)chunkB * 4096;
  u16* ao = vp + (size_t)chunkB * 4096;

  // expand circulant weights once per call
  expand_all<<<8192, 256, 0, stream>>>(w_q, w_k, w_v, w_fc, Wq, Wk, Wv, Wfc);

  for (int cs = 0; cs < B; cs += chunkB) {
    const int nb_p = (chunkB / 128) * (4096 / 128);
    gemm_qkv<<<dim3(nb_p, 3), 256, 0, stream>>>(
        q + (size_t)cs * 1024, k + (size_t)cs * 1024, v + (size_t)cs * 1024,
        Wq, Wk, Wv, b_q, b_k, b_v, qp, kp, vp, chunkB, 4096, 1024);
    const int ablocks = (chunkB >= 1024) ? 2048 : chunkB * 2;
    const int aiters = (chunkB * 8) / (ablocks * 4);
    attn_kernel<<<ablocks, 256, 0, stream>>>(qp, kp, vp,
                                             probs + (size_t)cs * 512, ao, aiters);
    const int nb_fc = (chunkB / 128) * (1024 / 64);
    gemm_fc<<<nb_fc, 256, 0, stream>>>(ao, Wfc, b_fc, q + (size_t)cs * 1024,
                                       out + (size_t)cs * 1024, chunkB, 1024,
                                       4096);
  }
}